// Round 5
// baseline (205.528 us; speedup 1.0000x reference)
//
#include <hip/hip_runtime.h>
#include <hip/hip_bf16.h>
#include <stdint.h>

typedef __attribute__((ext_vector_type(8))) short bf16x8;
typedef __attribute__((ext_vector_type(4))) short bf16x4;
typedef __attribute__((ext_vector_type(4))) float f32x4;

#define T_SEQ   8192
#define D_HEAD  64
#define NHEADS  16          // B*H
#define WIN     512
#define BQ      256         // q per block (4 waves x 64 q)
#define BK      64
#define NTILES  128         // T_SEQ/BK
#define NQT     32          // T_SEQ/BQ
#define TILE_SH 8192        // shorts per (head,tile) in KVf: Kf 4096 + Vf 4096 (16KB)
#define MASKVAL (-1.0e6f)

#define WS_NEEDED ((size_t)NHEADS * NTILES * TILE_SH * sizeof(short))   // 33.5 MB

#define MFMA32(a,b,c) __builtin_amdgcn_mfma_f32_16x16x32_bf16(a,b,c,0,0,0)

__device__ __forceinline__ short f2bf(float f) {
    union { float f; uint32_t u; } v; v.f = f;
    return (short)((v.u + 0x7FFFu + ((v.u >> 16) & 1u)) >> 16);   // RNE, finite inputs
}

__device__ __forceinline__ uint32_t pkbf2(float lo, float hi) {
    union { __hip_bfloat162 h; uint32_t u; } c;
    c.h = __float22bfloat162_rn(make_float2(lo, hi));             // v_cvt_pk_bf16_f32
    return c.u;
}

// ---------------- prep: K,V -> MFMA-fragment-ordered bf16 tiles in ws ----------------
// Per (head,tile) 16KB: shorts [0,4096): Kf, [4096,8192): Vf.
// Kf 16B-block b = ((kc*2+ks)*16+key)*4+quad : elem e = K[t*64+kc*16+key][ks*32+quad*8+e]
//   -> QK A-frag (m=key=lane&15, k=quad*8+e)  [layout HW-verified in r4]
// Vf 16B-block b = ((h*4+nt)*16+dl)*4+quad :
//   elems 0..3 = V[t*64+h*32+quad*4+j][nt*16+dl], elems 4..7 = V[t*64+h*32+16+quad*4+j][nt*16+dl]
//   -> PV A-frag (m=d=lane&15 within nt, k=quad*8+e) matching S^T C-rows of chunks 2h,2h+1
__global__ __launch_bounds__(256, 2)
void prep_kv(const float* __restrict__ Kg, const float* __restrict__ Vg,
             short* __restrict__ KVf)
{
    __shared__ float vt[64 * 65];
    const int tid  = threadIdx.x;
    const int tile = blockIdx.x & (NTILES - 1);
    const int head = blockIdx.x >> 7;
    const size_t off = ((size_t)head * T_SEQ + (size_t)tile * BK) * D_HEAD;
    short* KV = KVf + ((size_t)head * NTILES + tile) * TILE_SH;

    // stage V tile fp32 -> LDS (coalesced)
    const float* vs = Vg + off;
    #pragma unroll
    for (int i = 0; i < 4; ++i) {
        int idx = tid + 256 * i;
        int row = idx >> 4, c4 = (idx & 15) << 2;
        *(float4*)&vt[row * 65 + c4] = *(const float4*)(vs + row * D_HEAD + c4);
    }

    // K -> Kf (512 16B-blocks, 2/thread)
    const float* ksrc = Kg + off;
    #pragma unroll
    for (int i = 0; i < 2; ++i) {
        int b = tid + 256 * i;
        int quad = b & 3, key = (b >> 2) & 15, ks = (b >> 6) & 1, kc = b >> 7;
        const float* src = ksrc + (kc * 16 + key) * D_HEAD + ks * 32 + quad * 8;
        float4 a = *(const float4*)src;
        float4 c = *(const float4*)(src + 4);
        bf16x8 o;
        o[0]=f2bf(a.x); o[1]=f2bf(a.y); o[2]=f2bf(a.z); o[3]=f2bf(a.w);
        o[4]=f2bf(c.x); o[5]=f2bf(c.y); o[6]=f2bf(c.z); o[7]=f2bf(c.w);
        *(bf16x8*)(KV + b * 8) = o;
    }

    __syncthreads();

    // V -> Vf (512 16B-blocks, 2/thread)
    #pragma unroll
    for (int i = 0; i < 2; ++i) {
        int b = tid + 256 * i;
        int quad = b & 3, dl = (b >> 2) & 15, nt = (b >> 6) & 3, h = b >> 8;
        int col = nt * 16 + dl;
        bf16x8 o;
        #pragma unroll
        for (int j = 0; j < 4; ++j) o[j]     = f2bf(vt[(h*32 +      quad*4 + j) * 65 + col]);
        #pragma unroll
        for (int j = 0; j < 4; ++j) o[4 + j] = f2bf(vt[(h*32 + 16 + quad*4 + j) * 65 + col]);
        *(bf16x8*)(KV + 4096 + b * 8) = o;
    }
}

// ---------------- main: S^T = K Q^T, reg->PV direct, dbuf LDS, 1 barrier/tile ----------------
__global__ __launch_bounds__(256, 2)
void swa_fwd(const float* __restrict__ Qg, const short* __restrict__ KVf,
             float* __restrict__ Og)
{
    __shared__ __align__(16) short Buf[2][TILE_SH];   // 2 x 16KB

    const int tid  = threadIdx.x;
    const int wave = tid >> 6;
    const int lane = tid & 63;
    const int lcol = lane & 15;
    const int quad = lane >> 4;

    const int g    = blockIdx.x;
    const int head = ((g & 7) << 1) | ((g >> 3) & 1);   // XCD x -> heads {2x,2x+1}
    const int qt   = g >> 4;                            // 0..31
    const int q0   = qt * BQ;
    const int tb   = qt * 4;                            // q0/64

    const float* Qp  = Qg  + (size_t)head * T_SEQ * D_HEAD;
    float*       Op  = Og  + (size_t)head * T_SEQ * D_HEAD;
    const short* KVh = KVf + (size_t)head * NTILES * TILE_SH;

    const float qscale = 0.125f * 1.44269504088896340736f;  // 1/sqrt(D) * log2(e)
    const int qrow_w = q0 + wave * 64;

    // Q fragments (B-operand of K*Q^T): qf[mt][ks], rows qrow_w+mt*16+lcol
    bf16x8 qf[4][2];
    #pragma unroll
    for (int mt = 0; mt < 4; ++mt) {
        const float* qptr = Qp + (size_t)(qrow_w + mt*16 + lcol) * D_HEAD + quad * 8;
        #pragma unroll
        for (int ks = 0; ks < 2; ++ks) {
            float4 a = *(const float4*)(qptr + ks*32);
            float4 b = *(const float4*)(qptr + ks*32 + 4);
            bf16x8 f;
            f[0]=f2bf(a.x*qscale); f[1]=f2bf(a.y*qscale); f[2]=f2bf(a.z*qscale); f[3]=f2bf(a.w*qscale);
            f[4]=f2bf(b.x*qscale); f[5]=f2bf(b.y*qscale); f[6]=f2bf(b.z*qscale); f[7]=f2bf(b.w*qscale);
            qf[mt][ks] = f;
        }
    }

    f32x4 oacc[4][4];
    float l_run[4];
    const f32x4 zero4 = {0.f, 0.f, 0.f, 0.f};
    #pragma unroll
    for (int mt = 0; mt < 4; ++mt) {
        l_run[mt] = 0.f;
        #pragma unroll
        for (int nt = 0; nt < 4; ++nt) oacc[mt][nt] = zero4;
    }

    int t0 = tb - 8;  if (t0 < 0) t0 = 0;
    int t1 = tb + 11; if (t1 > NTILES - 1) t1 = NTILES - 1;

    // preload tile t0 into Buf[0] (flat 16KB copy, 4 x b128 per thread)
    {
        const short* src = KVh + (size_t)t0 * TILE_SH + tid * 8;
        #pragma unroll
        for (int i = 0; i < 4; ++i)
            *(bf16x8*)&Buf[0][tid*8 + i*2048] = *(const bf16x8*)(src + i*2048);
    }
    __syncthreads();

    int cur = 0;
    for (int t = t0; t <= t1; ++t) {
        // prefetch next tile into registers (consumed at loop bottom)
        bf16x8 pre[4];
        const bool have = (t < t1);
        if (have) {
            const short* src = KVh + (size_t)(t + 1) * TILE_SH + tid * 8;
            #pragma unroll
            for (int i = 0; i < 4; ++i) pre[i] = *(const bf16x8*)(src + i*2048);
        }

        // wave-uniform activity: skip compute if this wave's q-range can't see tile t
        if (t*BK <= qrow_w + 63 + WIN && t*BK + 63 >= qrow_w - WIN) {
            const short* Kl = Buf[cur];
            const short* Vl = Buf[cur] + 4096;
            const bool edge = (t < tb - 4) || (t > tb + 7);

            #pragma unroll
            for (int h = 0; h < 2; ++h) {        // 32-key groups
                bf16x4 pq[2][4];                  // packed P: [16-key chunk jj][mt]
                #pragma unroll
                for (int jj = 0; jj < 2; ++jj) {
                    const int kc = h*2 + jj;
                    bf16x8 kf0 = *(const bf16x8*)&Kl[((kc*2 + 0)*64 + lcol*4 + quad) * 8];
                    bf16x8 kf1 = *(const bf16x8*)&Kl[((kc*2 + 1)*64 + lcol*4 + quad) * 8];
                    f32x4 sc[4];
                    #pragma unroll
                    for (int mt = 0; mt < 4; ++mt) sc[mt] = zero4;
                    #pragma unroll
                    for (int mt = 0; mt < 4; ++mt) {
                        sc[mt] = MFMA32(kf0, qf[mt][0], sc[mt]);
                        sc[mt] = MFMA32(kf1, qf[mt][1], sc[mt]);
                    }
                    if (edge) {
                        const int kg0 = t*BK + kc*16 + quad*4;
                        #pragma unroll
                        for (int mt = 0; mt < 4; ++mt) {
                            const int qg = qrow_w + mt*16 + lcol;
                            #pragma unroll
                            for (int r = 0; r < 4; ++r) {
                                int dq = qg - (kg0 + r);
                                if (dq > WIN || dq < -WIN) sc[mt][r] = MASKVAL;
                            }
                        }
                    }
                    #pragma unroll
                    for (int mt = 0; mt < 4; ++mt) {
                        float p0 = exp2f(sc[mt][0]), p1 = exp2f(sc[mt][1]);
                        float p2 = exp2f(sc[mt][2]), p3 = exp2f(sc[mt][3]);
                        l_run[mt] += (p0 + p1) + (p2 + p3);
                        union { int2 i2; bf16x4 v; } u;
                        u.i2 = make_int2((int)pkbf2(p0, p1), (int)pkbf2(p2, p3));
                        pq[jj][mt] = u.v;
                    }
                }
                // PV for the 32-key group: P^T chunks concat -> 16x16x32 B-frag
                bf16x8 pf[4];
                #pragma unroll
                for (int mt = 0; mt < 4; ++mt) {
                    union { bf16x8 v; bf16x4 q[2]; } u;
                    u.q[0] = pq[0][mt]; u.q[1] = pq[1][mt];
                    pf[mt] = u.v;
                }
                #pragma unroll
                for (int nt = 0; nt < 4; ++nt) {
                    bf16x8 vf = *(const bf16x8*)&Vl[((h*4 + nt)*64 + lcol*4 + quad) * 8];
                    #pragma unroll
                    for (int mt = 0; mt < 4; ++mt)
                        oacc[mt][nt] = MFMA32(vf, pf[mt], oacc[mt][nt]);
                }
            }
        }

        // write prefetched tile into the other buffer; one barrier per tile
        if (have) {
            #pragma unroll
            for (int i = 0; i < 4; ++i)
                *(bf16x8*)&Buf[cur ^ 1][tid*8 + i*2048] = pre[i];
        }
        __syncthreads();
        cur ^= 1;
    }

    // epilogue: reduce l over quads, store O[q][d] as contiguous float4
    #pragma unroll
    for (int mt = 0; mt < 4; ++mt) {
        float l = l_run[mt];
        l += __shfl_xor(l, 16, 64);
        l += __shfl_xor(l, 32, 64);
        float inv = 1.0f / l;
        const int qg = qrow_w + mt*16 + lcol;
        float* op = Op + (size_t)qg * D_HEAD + quad*4;
        #pragma unroll
        for (int nt = 0; nt < 4; ++nt) {
            float4 o = { oacc[mt][nt][0]*inv, oacc[mt][nt][1]*inv,
                         oacc[mt][nt][2]*inv, oacc[mt][nt][3]*inv };
            *(float4*)(op + nt*16) = o;
        }
    }
}

// ---------------- fallback (ws too small): round-1 fp32-staging kernel, known correct ----------------
#define LDSR    72
#define M_INIT  (-1.0e4f)
__global__ __launch_bounds__(256, 2)
void swa_fwd_fb(const float* __restrict__ Qg, const float* __restrict__ Kg,
                const float* __restrict__ Vg, float* __restrict__ Og)
{
    __shared__ short Ks[BK * LDSR];
    __shared__ short Vs[D_HEAD * LDSR];
    __shared__ short Ps[4 * 32 * LDSR];

    const int tid  = threadIdx.x;
    const int wave = tid >> 6;
    const int lane = tid & 63;
    const int lcol = lane & 15;
    const int quad = lane >> 4;

    const int g    = blockIdx.x;
    const int head = (g >> 3) >> 3;
    const int qt   = ((g & 7) << 3) | ((g >> 3) & 7);
    const int q0   = qt * 128;

    const size_t base = (size_t)head * T_SEQ * D_HEAD;
    const float* Qp = Qg + base;
    const float* Kp = Kg + base;
    const float* Vp = Vg + base;
    float*       Op = Og + base;

    const float qscale = 0.125f * 1.44269504088896340736f;
    const int qrow_w = q0 + wave * 32;

    bf16x8 qf[2][2];
    #pragma unroll
    for (int mt = 0; mt < 2; ++mt) {
        const float* qptr = Qp + (size_t)(qrow_w + mt*16 + lcol) * D_HEAD + quad * 8;
        #pragma unroll
        for (int ks = 0; ks < 2; ++ks) {
            float4 a = *(const float4*)(qptr + ks*32);
            float4 b = *(const float4*)(qptr + ks*32 + 4);
            bf16x8 f;
            f[0]=f2bf(a.x*qscale); f[1]=f2bf(a.y*qscale); f[2]=f2bf(a.z*qscale); f[3]=f2bf(a.w*qscale);
            f[4]=f2bf(b.x*qscale); f[5]=f2bf(b.y*qscale); f[6]=f2bf(b.z*qscale); f[7]=f2bf(b.w*qscale);
            qf[mt][ks] = f;
        }
    }

    f32x4 oacc[2][4];
    float m_run[2][4], l_run[2][4];
    const f32x4 zero4 = {0.f, 0.f, 0.f, 0.f};
    #pragma unroll
    for (int mt = 0; mt < 2; ++mt) {
        #pragma unroll
        for (int r = 0; r < 4; ++r) { m_run[mt][r] = M_INIT; l_run[mt][r] = 0.f; }
        #pragma unroll
        for (int nt = 0; nt < 4; ++nt) oacc[mt][nt] = zero4;
    }

    int t0 = (q0 - WIN) >> 6;            if (t0 < 0) t0 = 0;
    int t1 = (q0 + 127 + WIN) >> 6;      if (t1 > NTILES - 1) t1 = NTILES - 1;

    for (int t = t0; t <= t1; ++t) {
        __syncthreads();
        {
            const float* src = Kp + (size_t)t * BK * D_HEAD;
            #pragma unroll
            for (int i = 0; i < 4; ++i) {
                int f4 = tid + 256*i;
                int row = f4 >> 4, c4 = (f4 & 15) << 2;
                float4 v = *(const float4*)(src + row*D_HEAD + c4);
                short4 hh = { f2bf(v.x), f2bf(v.y), f2bf(v.z), f2bf(v.w) };
                *(short4*)&Ks[row*LDSR + c4] = hh;
            }
            const float* vsrc = Vp + (size_t)t * BK * D_HEAD;
            int col = tid & 63, rb = (tid >> 6) << 2;
            #pragma unroll
            for (int i = 0; i < 4; ++i) {
                int r = rb + 16*i;
                short4 hh = { f2bf(vsrc[(r+0)*D_HEAD + col]),
                              f2bf(vsrc[(r+1)*D_HEAD + col]),
                              f2bf(vsrc[(r+2)*D_HEAD + col]),
                              f2bf(vsrc[(r+3)*D_HEAD + col]) };
                *(short4*)&Vs[col*LDSR + r] = hh;
            }
        }
        __syncthreads();

        f32x4 sc[2][4];
        #pragma unroll
        for (int mt = 0; mt < 2; ++mt)
            #pragma unroll
            for (int kt = 0; kt < 4; ++kt) sc[mt][kt] = zero4;
        #pragma unroll
        for (int kt = 0; kt < 4; ++kt) {
            #pragma unroll
            for (int ks = 0; ks < 2; ++ks) {
                bf16x8 kf = *(const bf16x8*)&Ks[(kt*16 + lcol)*LDSR + ks*32 + quad*8];
                sc[0][kt] = MFMA32(qf[0][ks], kf, sc[0][kt]);
                sc[1][kt] = MFMA32(qf[1][ks], kf, sc[1][kt]);
            }
        }

        const int kb = t * BK + lcol;
        #pragma unroll
        for (int mt = 0; mt < 2; ++mt) {
            const int qrow = qrow_w + mt*16 + quad*4;
            #pragma unroll
            for (int kt = 0; kt < 4; ++kt) {
                int kg = kb + kt*16;
                #pragma unroll
                for (int r = 0; r < 4; ++r) {
                    int dq = (qrow + r) - kg;
                    if (dq > WIN || dq < -WIN) sc[mt][kt][r] = MASKVAL;
                }
            }
            float tm[4], al[4], rs[4];
            #pragma unroll
            for (int r = 0; r < 4; ++r)
                tm[r] = fmaxf(fmaxf(sc[mt][0][r], sc[mt][1][r]), fmaxf(sc[mt][2][r], sc[mt][3][r]));
            #pragma unroll
            for (int off = 1; off < 16; off <<= 1)
                #pragma unroll
                for (int r = 0; r < 4; ++r)
                    tm[r] = fmaxf(tm[r], __shfl_xor(tm[r], off, 64));
            #pragma unroll
            for (int r = 0; r < 4; ++r) {
                float mn = fmaxf(m_run[mt][r], tm[r]);
                al[r] = exp2f(m_run[mt][r] - mn);
                m_run[mt][r] = mn;
                rs[r] = 0.f;
            }
            #pragma unroll
            for (int kt = 0; kt < 4; ++kt)
                #pragma unroll
                for (int r = 0; r < 4; ++r) {
                    float p = exp2f(sc[mt][kt][r] - m_run[mt][r]);
                    sc[mt][kt][r] = p;
                    rs[r] += p;
                }
            #pragma unroll
            for (int off = 1; off < 16; off <<= 1)
                #pragma unroll
                for (int r = 0; r < 4; ++r)
                    rs[r] += __shfl_xor(rs[r], off, 64);
            #pragma unroll
            for (int r = 0; r < 4; ++r)
                l_run[mt][r] = l_run[mt][r]*al[r] + rs[r];
            #pragma unroll
            for (int nt = 0; nt < 4; ++nt)
                #pragma unroll
                for (int r = 0; r < 4; ++r) oacc[mt][nt][r] *= al[r];
            short* pw = &Ps[(wave*32 + mt*16 + quad*4) * LDSR];
            #pragma unroll
            for (int kt = 0; kt < 4; ++kt)
                #pragma unroll
                for (int r = 0; r < 4; ++r)
                    pw[r*LDSR + kt*16 + lcol] = f2bf(sc[mt][kt][r]);
        }

        const short* pr = &Ps[wave*32*LDSR];
        #pragma unroll
        for (int ks = 0; ks < 2; ++ks) {
            bf16x8 pf0 = *(const bf16x8*)&pr[(lcol     )*LDSR + ks*32 + quad*8];
            bf16x8 pf1 = *(const bf16x8*)&pr[(16 + lcol)*LDSR + ks*32 + quad*8];
            #pragma unroll
            for (int nt = 0; nt < 4; ++nt) {
                bf16x8 vf = *(const bf16x8*)&Vs[(nt*16 + lcol)*LDSR + ks*32 + quad*8];
                oacc[0][nt] = MFMA32(pf0, vf, oacc[0][nt]);
                oacc[1][nt] = MFMA32(pf1, vf, oacc[1][nt]);
            }
        }
    }

    #pragma unroll
    for (int mt = 0; mt < 2; ++mt)
        #pragma unroll
        for (int r = 0; r < 4; ++r) {
            int row = qrow_w + mt*16 + quad*4 + r;
            float inv = 1.0f / l_run[mt][r];
            float* op = Op + (size_t)row * D_HEAD + lcol;
            #pragma unroll
            for (int nt = 0; nt < 4; ++nt)
                op[nt*16] = oacc[mt][nt][r] * inv;
        }
}

extern "C" void kernel_launch(void* const* d_in, const int* in_sizes, int n_in,
                              void* d_out, int out_size, void* d_ws, size_t ws_size,
                              hipStream_t stream)
{
    const float* Q = (const float*)d_in[0];
    const float* K = (const float*)d_in[1];
    const float* V = (const float*)d_in[2];
    float* O = (float*)d_out;

    if (ws_size >= WS_NEEDED) {
        short* KVf = (short*)d_ws;
        prep_kv<<<dim3(NHEADS * NTILES), dim3(256), 0, stream>>>(K, V, KVf);
        swa_fwd<<<dim3(NHEADS * NQT), dim3(256), 0, stream>>>(Q, KVf, O);
    } else {
        swa_fwd_fb<<<dim3(NHEADS * 64), dim3(256), 0, stream>>>(Q, K, V, O);
    }
}